// Round 2
// baseline (47318.967 us; speedup 1.0000x reference)
//
#include <hip/hip_runtime.h>

// Problem sizes (fixed by the reference)
constexpr int B = 128, S = 1024, E = 256, H = 512, V = 128;
constexpr int NWG = 240;

// LDS tile: weights 64 rows x 64 k (as float4, XOR-swizzled), activations 16 rows x 64 k.
struct SMem {
  float4 Ws4[64 * 16];  // [row n(64)][k-chunk c(16)], chunk idx XOR (n&15) -> conflict-free b128
  float  Hs[16 * 68];   // [b(16)][k(64)] rows padded to 68 floats (16B-aligned rows)
};

// Hand-rolled grid barrier. bar[0]=arrive counter, bar[1]=generation.
// Requires all NWG blocks co-resident (cooperative launch).
__device__ __forceinline__ void gsync(unsigned* bar, int tid) {
  __syncthreads();
  if (tid == 0) {
    unsigned* cnt = bar;
    unsigned* gen = bar + 1;
    unsigned g = __hip_atomic_load(gen, __ATOMIC_RELAXED, __HIP_MEMORY_SCOPE_AGENT);
    // release our writes + arrive
    if (__hip_atomic_fetch_add(cnt, 1u, __ATOMIC_ACQ_REL, __HIP_MEMORY_SCOPE_AGENT) == NWG - 1u) {
      __hip_atomic_store(cnt, 0u, __ATOMIC_RELAXED, __HIP_MEMORY_SCOPE_AGENT);
      __hip_atomic_store(gen, g + 1u, __ATOMIC_RELEASE, __HIP_MEMORY_SCOPE_AGENT);
    } else {
      while (__hip_atomic_load(gen, __ATOMIC_ACQUIRE, __HIP_MEMORY_SCOPE_AGENT) == g) {
        __builtin_amdgcn_s_sleep(2);
      }
    }
  }
  __syncthreads();
}

// MODE 0: act rows gathered from emb via x, add bias1+bias2            (Ain)
// MODE 1: act rows from A, add init matrix, tanh                       (h0,h1 recurrent)
// MODE 2: act rows from A, add bias1+bias2                             (G)
// MODE 3: act rows from A, add bias1                                   (logits)
template <int MODE>
__device__ __forceinline__ void mm_tile(
    int tid,
    const float* A, int lda,          // MODE!=0: row b at A + (b0+b)*lda
    const int* gidx,                  // MODE==0: row b = emb + x[(b0+b)*S + t]*E  (gidx = x + t)
    const float* gtab,
    const float* W, int K,            // W[n][k] row-major
    const float* bias1, const float* bias2,
    const float* initm,               // MODE==1: init[(b0+b)*H + n0+n]
    float* C, size_t ldc,
    int b0, int n0, SMem& sm)
{
  const int h  = tid & 63;
  const int bg = tid >> 6;  // 0..3
  float acc0, acc1, acc2, acc3;
  if (MODE == 1) {
    acc0 = initm[(size_t)(b0 + bg +  0) * H + n0 + h];
    acc1 = initm[(size_t)(b0 + bg +  4) * H + n0 + h];
    acc2 = initm[(size_t)(b0 + bg +  8) * H + n0 + h];
    acc3 = initm[(size_t)(b0 + bg + 12) * H + n0 + h];
  } else {
    float v = bias1[n0 + h];
    if (MODE != 3) v += bias2[n0 + h];
    acc0 = acc1 = acc2 = acc3 = v;
  }

  for (int k0 = 0; k0 < K; k0 += 64) {
    __syncthreads();
    {
      // Stage weight tile: 64 rows x 16 float4 = 1024 float4 / 256 thr = 4 each.
      const int c  = tid & 15;
      const int hh = tid >> 4;
      for (int it = 0; it < 4; ++it) {
        int hr = hh + it * 16;
        float4 wv = *(const float4*)(W + (size_t)(n0 + hr) * K + k0 + 4 * c);
        sm.Ws4[hr * 16 + (c ^ (hr & 15))] = wv;
      }
      // Stage activation rows: 16 rows x 1 float4 per thread.
      const int b = tid >> 4;
      const float* row;
      if (MODE == 0) row = gtab + (size_t)gidx[(size_t)(b0 + b) * S] * lda;
      else           row = A + (size_t)(b0 + b) * lda;
      *(float4*)(sm.Hs + b * 68 + 4 * c) = *(const float4*)(row + k0 + 4 * c);
    }
    __syncthreads();

    for (int k4 = 0; k4 < 16; ++k4) {
      float4 w4 = sm.Ws4[h * 16 + (k4 ^ (h & 15))];
      const float* x0 = sm.Hs + (bg +  0) * 68 + 4 * k4;
      const float* x1 = sm.Hs + (bg +  4) * 68 + 4 * k4;
      const float* x2 = sm.Hs + (bg +  8) * 68 + 4 * k4;
      const float* x3 = sm.Hs + (bg + 12) * 68 + 4 * k4;
      acc0 += x0[0] * w4.x + x0[1] * w4.y + x0[2] * w4.z + x0[3] * w4.w;
      acc1 += x1[0] * w4.x + x1[1] * w4.y + x1[2] * w4.z + x1[3] * w4.w;
      acc2 += x2[0] * w4.x + x2[1] * w4.y + x2[2] * w4.z + x2[3] * w4.w;
      acc3 += x3[0] * w4.x + x3[1] * w4.y + x3[2] * w4.z + x3[3] * w4.w;
    }
  }

  if (MODE == 1) {
    acc0 = tanhf(acc0); acc1 = tanhf(acc1); acc2 = tanhf(acc2); acc3 = tanhf(acc3);
  }
  C[(size_t)(b0 + bg +  0) * ldc + n0 + h] = acc0;
  C[(size_t)(b0 + bg +  4) * ldc + n0 + h] = acc1;
  C[(size_t)(b0 + bg +  8) * ldc + n0 + h] = acc2;
  C[(size_t)(b0 + bg + 12) * ldc + n0 + h] = acc3;
}

// Persistent pipelined RNN. Phase p computes:
//   wgs [0,32)   : Ain[t=p]   = (b_ih0+b_hh0) + emb[x[:,t]] @ W_ih0^T      (K=256, 2 tiles)
//   wgs [32,96)  : h0[t=p-1]  = tanh(Ain[t] + h0[t-1] @ W_hh0^T)           (K=512)
//   wgs [96,160) : G[t=p-2]   = (b_ih1+b_hh1) + h0[t] @ W_ih1^T            (K=512)
//   wgs [160,224): h1[t=p-3]  = tanh(G[t] + h1[t-1] @ W_hh1^T)             (K=512)
//   wgs [224,240): logits[t=p-4] = b_out + h1[t] @ W_out^T                 (K=512)
// Every read is of data written in an earlier phase -> one gsync per phase.
__global__ void __launch_bounds__(256, 1) rnn_persistent(
    const int* __restrict__ x, const float* __restrict__ emb,
    const float* __restrict__ W_ih0, const float* __restrict__ b_ih0,
    const float* __restrict__ W_hh0, const float* __restrict__ b_hh0,
    const float* __restrict__ W_ih1, const float* __restrict__ b_ih1,
    const float* __restrict__ W_hh1, const float* __restrict__ b_hh1,
    const float* __restrict__ W_out, const float* __restrict__ b_out,
    float* __restrict__ out, float* __restrict__ ws)
{
  __shared__ SMem sm;
  const int w = blockIdx.x;
  const int tid = threadIdx.x;

  unsigned* bar = (unsigned*)ws;          // ws[0..1], zeroed by hipMemsetAsync
  const size_t BH = (size_t)B * H;
  float* Ain = ws + 16;                   // [2][B][H]
  float* h0  = Ain + 2 * BH;              // [2][B][H]
  float* G   = h0 + 2 * BH;               // [2][B][H]
  float* h1  = G + 2 * BH;                // [2][B][H]

  // Zero initial hidden states (both slots; slot 1 is the t=-1 state).
  {
    size_t nid = (size_t)w * 256 + tid;
    size_t tot = (size_t)NWG * 256;
    for (size_t i = nid; i < 2 * BH; i += tot) { h0[i] = 0.f; h1[i] = 0.f; }
  }
  gsync(bar, tid);

  for (int p = 0; p <= S + 3; ++p) {
    if (w < 32) {
      int t = p;
      if (t < S) {
        float* C = Ain + (size_t)(t & 1) * BH;
        for (int q = 0; q < 2; ++q) {
          int id = w * 2 + q;             // 0..63 : 8 b-tiles x 8 h-tiles
          int tb = id >> 3, th = id & 7;
          mm_tile<0>(tid, nullptr, E, x + t, emb, W_ih0, E,
                     b_ih0, b_hh0, nullptr, C, H, tb * 16, th * 64, sm);
        }
      }
    } else if (w < 96) {
      int t = p - 1;
      if (t >= 0 && t < S) {
        int id = w - 32, tb = id >> 3, th = id & 7;
        const float* hp = h0 + (size_t)((t - 1) & 1) * BH;  // t=0 -> zeroed slot 1
        const float* im = Ain + (size_t)(t & 1) * BH;
        float* C = h0 + (size_t)(t & 1) * BH;
        mm_tile<1>(tid, hp, H, nullptr, nullptr, W_hh0, H,
                   nullptr, nullptr, im, C, H, tb * 16, th * 64, sm);
      }
    } else if (w < 160) {
      int t = p - 2;
      if (t >= 0 && t < S) {
        int id = w - 96, tb = id >> 3, th = id & 7;
        const float* hp = h0 + (size_t)(t & 1) * BH;
        float* C = G + (size_t)(t & 1) * BH;
        mm_tile<2>(tid, hp, H, nullptr, nullptr, W_ih1, H,
                   b_ih1, b_hh1, nullptr, C, H, tb * 16, th * 64, sm);
      }
    } else if (w < 224) {
      int t = p - 3;
      if (t >= 0 && t < S) {
        int id = w - 160, tb = id >> 3, th = id & 7;
        const float* hp = h1 + (size_t)((t - 1) & 1) * BH;
        const float* im = G + (size_t)(t & 1) * BH;
        float* C = h1 + (size_t)(t & 1) * BH;
        mm_tile<1>(tid, hp, H, nullptr, nullptr, W_hh1, H,
                   nullptr, nullptr, im, C, H, tb * 16, th * 64, sm);
      }
    } else {
      int t = p - 4;
      if (t >= 0 && t < S) {
        int id = w - 224, tb = id >> 1, tv = id & 1;  // 8 b-tiles x 2 v-tiles
        const float* hp = h1 + (size_t)(t & 1) * BH;
        mm_tile<3>(tid, hp, H, nullptr, nullptr, W_out, H,
                   b_out, nullptr, nullptr, out + (size_t)t * V, (size_t)S * V,
                   tb * 16, tv * 64, sm);
      }
    }
    gsync(bar, tid);
  }

  // h_n = [h0[S-1], h1[S-1]] appended after logits.
  {
    float* hn = out + (size_t)B * S * V;
    const float* h0f = h0 + (size_t)((S - 1) & 1) * BH;
    const float* h1f = h1 + (size_t)((S - 1) & 1) * BH;
    size_t nid = (size_t)w * 256 + tid;
    size_t tot = (size_t)NWG * 256;
    for (size_t i = nid; i < BH; i += tot) {
      hn[i] = h0f[i];
      hn[BH + i] = h1f[i];
    }
  }
}

extern "C" void kernel_launch(void* const* d_in, const int* in_sizes, int n_in,
                              void* d_out, int out_size, void* d_ws, size_t ws_size,
                              hipStream_t stream) {
  const int*   x     = (const int*)d_in[0];
  const float* emb   = (const float*)d_in[1];
  const float* W_ih0 = (const float*)d_in[2];
  const float* b_ih0 = (const float*)d_in[3];
  const float* W_hh0 = (const float*)d_in[4];
  const float* b_hh0 = (const float*)d_in[5];
  const float* W_ih1 = (const float*)d_in[6];
  const float* b_ih1 = (const float*)d_in[7];
  const float* W_hh1 = (const float*)d_in[8];
  const float* b_hh1 = (const float*)d_in[9];
  const float* W_out = (const float*)d_in[10];
  const float* b_out = (const float*)d_in[11];
  float* out = (float*)d_out;
  float* ws  = (float*)d_ws;

  // Zero the grid-barrier state (ws is poisoned to 0xAA by the harness).
  hipMemsetAsync(ws, 0, 2 * sizeof(unsigned), stream);

  void* args[] = { &x, &emb, &W_ih0, &b_ih0, &W_hh0, &b_hh0, &W_ih1, &b_ih1,
                   &W_hh1, &b_hh1, &W_out, &b_out, &out, &ws };
  hipLaunchCooperativeKernel((const void*)rnn_persistent, dim3(NWG), dim3(256),
                             args, 0, stream);
}

// Round 3
// 25827.621 us; speedup vs baseline: 1.8321x; 1.8321x over previous
//
#include <hip/hip_runtime.h>

// Problem sizes (fixed by the reference)
constexpr int B = 128, S = 1024, E = 256, H = 512, V = 128;
constexpr int NGROUP = 4, WPG = 60, NWG = NGROUP * WPG;  // 4 independent batch groups
constexpr int GB = B / NGROUP;          // 32 batches per group
constexpr int GBH = GB * H;             // floats per (group, slot)
constexpr unsigned LDS_BYTES = 163840;  // 128KB weights + 32KB acts/reduce == 160KB

// Group-local all-to-all flag barrier: no RMW, no master. Each WG stores its
// phase counter to its own slot (release); all WGs poll all 60 slots with one
// per-lane load until min >= target (acquire fence on exit).
__device__ __forceinline__ void gbar(unsigned* slots, int myslot, unsigned target, int tid) {
  __syncthreads();
  if (tid < 64) {
    if (tid == 0) {
      __builtin_amdgcn_fence(__ATOMIC_RELEASE, "agent");
      __hip_atomic_store(slots + myslot, target, __ATOMIC_RELAXED, __HIP_MEMORY_SCOPE_AGENT);
    }
    for (;;) {
      unsigned v = (tid < WPG)
        ? __hip_atomic_load(slots + tid, __ATOMIC_RELAXED, __HIP_MEMORY_SCOPE_AGENT)
        : target;
      if (__all(v >= target)) break;
      __builtin_amdgcn_s_sleep(1);
    }
    __builtin_amdgcn_fence(__ATOMIC_ACQUIRE, "agent");
  }
  __syncthreads();
}

// Preload a 64-col x KK-k fp32 weight tile into LDS, XOR-swizzled per 16-float4
// window (round-2-verified conflict-free pattern for the per-lane b128 reads).
template <int KK>
__device__ __forceinline__ void preload_W(int tid, const float* W, int n0, float4* W4dst) {
  constexpr int KC = KK / 4;
  for (int i = tid; i < 64 * KC; i += 256) {
    int c = i / KC, kc = i - c * KC;
    int swz = (kc & ~15) | ((kc ^ c) & 15);
    W4dst[c * KC + swz] = *(const float4*)(W + (size_t)(n0 + c) * KK + 4 * kc);
  }
}

// One 16b x 64n output tile, K=KK, weights resident in LDS (W4).
// Waves k-split (wave q owns KC/4 chunks); partials reduced via LDS (aliases A4).
// MODE 0: acts = emb rows gathered via xs[r*S]; + bias1+bias2        (Ain)
// MODE 1: acts from A; + initm; tanh                                 (h0/h1)
// MODE 2: acts from A; + bias1+bias2                                 (G)
// MODE 3: acts from A; + bias1                                       (logits)
template <int KK, int MODE>
__device__ __forceinline__ void tile_mm(
    int tid,
    const float* A,                    // MODE!=0: act row base, stride H
    const int* xs, const float* emb,   // MODE==0
    const float* bias1, const float* bias2,
    const float* initm, size_t ldi,    // MODE==1
    float* C, size_t ldc,
    const float4* W4, float4* A4)
{
  constexpr int KC = KK / 4;
  // stage acts: 16 rows x KC float4, coalesced
  for (int i = tid; i < 16 * KC; i += 256) {
    int rr = i / KC, kc = i - rr * KC;
    const float* row = (MODE == 0) ? (emb + (size_t)xs[(size_t)rr * S] * E)
                                   : (A + (size_t)rr * H);
    A4[i] = *(const float4*)(row + 4 * kc);
  }
  __syncthreads();

  const int c = tid & 63, q = tid >> 6;
  constexpr int SL = KC / 4;  // k-chunks per wave
  float acc[16];
#pragma unroll
  for (int rr = 0; rr < 16; ++rr) acc[rr] = 0.f;

  const int kc0 = q * SL;
  for (int kc = kc0; kc < kc0 + SL; ++kc) {
    float4 w4 = W4[c * KC + ((kc & ~15) | ((kc ^ c) & 15))];
#pragma unroll
    for (int rr = 0; rr < 16; ++rr) {
      float4 a4 = A4[rr * KC + kc];  // wave-uniform -> broadcast
      acc[rr] += w4.x * a4.x + w4.y * a4.y + w4.z * a4.z + w4.w * a4.w;
    }
  }

  __syncthreads();                 // acts consumed; reuse A4 as reduce buffer
  float* red = (float*)A4;
#pragma unroll
  for (int rr = 0; rr < 16; ++rr) red[(q * 16 + rr) * 64 + c] = acc[rr];
  __syncthreads();

#pragma unroll
  for (int j = 0; j < 4; ++j) {
    int o = tid + j * 256;
    int rr = o >> 6, cc = o & 63;
    float v = red[rr * 64 + cc] + red[(16 + rr) * 64 + cc] +
              red[(32 + rr) * 64 + cc] + red[(48 + rr) * 64 + cc];
    if (MODE == 1)      v = tanhf(v + initm[(size_t)rr * ldi + cc]);
    else if (MODE == 3) v += bias1[cc];
    else                v += bias1[cc] + bias2[cc];
    C[(size_t)rr * ldc + cc] = v;
  }
  __syncthreads();  // protect A4 before any same-phase second tile restages
}

// Roles within a 60-WG group:
//  r [0,16)  : h0-stage  t=p-1   h0[t]=tanh(Ain[t] + h0[t-1]@W_hh0^T)
//  r [16,32) : G-stage   t=p-2   G[t]=b_ih1+b_hh1 + h0[t]@W_ih1^T
//  r [32,48) : h1-stage  t=p-3   h1[t]=tanh(G[t] + h1[t-1]@W_hh1^T)
//  r [48,56) : Ain-stage t=p     Ain[t]=b_ih0+b_hh0 + emb[x[:,t]]@W_ih0^T (2 tiles)
//  r [56,60) : logits    t=p-4   out[t]=b_out + h1[t]@W_out^T
__global__ void __launch_bounds__(256, 1) rnn_pers(
    const int* x, const float* emb,
    const float* W_ih0, const float* b_ih0, const float* W_hh0, const float* b_hh0,
    const float* W_ih1, const float* b_ih1, const float* W_hh1, const float* b_hh1,
    const float* W_out, const float* b_out,
    float* out, float* ws)
{
  extern __shared__ float4 dynlds[];
  float4* W4 = dynlds;          // 8192 float4 (128KB)
  float4* A4 = dynlds + 8192;   // 2048 float4 (32KB), reduce buffer aliases

  const int tid = threadIdx.x;
  const int g = blockIdx.x / WPG;
  const int r = blockIdx.x % WPG;
  unsigned* slots = (unsigned*)ws + (size_t)g * 64;
  float* gbuf = ws + 256 + (size_t)g * (8 * (size_t)GBH);
  float* Ain = gbuf;                // [2][GB][H]
  float* h0  = gbuf + 2 * (size_t)GBH;
  float* Gg  = gbuf + 4 * (size_t)GBH;
  float* h1  = gbuf + 6 * (size_t)GBH;
  const int gb0 = g * GB;

  // Preload this WG's permanent weight tile(s) into LDS.
  int role, tb, tn;
  if (r < 16)      { role = 1; tb = r >> 3;        tn = r & 7;
                     preload_W<H>(tid, W_hh0, tn * 64, W4); }
  else if (r < 32) { role = 2; tb = (r - 16) >> 3; tn = (r - 16) & 7;
                     preload_W<H>(tid, W_ih1, tn * 64, W4); }
  else if (r < 48) { role = 3; tb = (r - 32) >> 3; tn = (r - 32) & 7;
                     preload_W<H>(tid, W_hh1, tn * 64, W4); }
  else if (r < 56) { int id = (r - 48) * 2; role = 0; tb = id >> 3; tn = id & 7;
                     preload_W<E>(tid, W_ih0, tn * 64, W4);
                     preload_W<E>(tid, W_ih0, (tn + 1) * 64, W4 + 4096); }
  else             { int id = r - 56; role = 4; tb = id >> 1; tn = id & 1;
                     preload_W<H>(tid, W_out, tn * 64, W4); }

  // Zero both slots of h0/h1 for this group.
  for (size_t i = (size_t)r * 256 + tid; i < 2 * (size_t)GBH; i += (size_t)WPG * 256) {
    h0[i] = 0.f; h1[i] = 0.f;
  }
  unsigned bt = 1;
  gbar(slots, r, bt++, tid);

  for (int p = 0; p <= S + 3; ++p) {
    if (role == 1) {
      int t = p - 1;
      if (t >= 0 && t < S) {
        const float* hp = h0 + (size_t)((t - 1) & 1) * GBH + (size_t)tb * 16 * H;
        const float* im = Ain + (size_t)(t & 1) * GBH + (size_t)tb * 16 * H + tn * 64;
        float* C = h0 + (size_t)(t & 1) * GBH + (size_t)tb * 16 * H + tn * 64;
        tile_mm<H, 1>(tid, hp, nullptr, nullptr, nullptr, nullptr, im, H, C, H, W4, A4);
      }
    } else if (role == 2) {
      int t = p - 2;
      if (t >= 0 && t < S) {
        const float* hp = h0 + (size_t)(t & 1) * GBH + (size_t)tb * 16 * H;
        float* C = Gg + (size_t)(t & 1) * GBH + (size_t)tb * 16 * H + tn * 64;
        tile_mm<H, 2>(tid, hp, nullptr, nullptr, b_ih1 + tn * 64, b_hh1 + tn * 64,
                      nullptr, 0, C, H, W4, A4);
      }
    } else if (role == 3) {
      int t = p - 3;
      if (t >= 0 && t < S) {
        const float* hp = h1 + (size_t)((t - 1) & 1) * GBH + (size_t)tb * 16 * H;
        const float* im = Gg + (size_t)(t & 1) * GBH + (size_t)tb * 16 * H + tn * 64;
        float* C = h1 + (size_t)(t & 1) * GBH + (size_t)tb * 16 * H + tn * 64;
        tile_mm<H, 1>(tid, hp, nullptr, nullptr, nullptr, nullptr, im, H, C, H, W4, A4);
      }
    } else if (role == 0) {
      int t = p;
      if (t < S) {
        const int* xs = x + (size_t)(gb0 + tb * 16) * S + t;
        float* Cb = Ain + (size_t)(t & 1) * GBH + (size_t)tb * 16 * H;
        tile_mm<E, 0>(tid, nullptr, xs, emb, b_ih0 + tn * 64, b_hh0 + tn * 64,
                      nullptr, 0, Cb + tn * 64, H, W4, A4);
        tile_mm<E, 0>(tid, nullptr, xs, emb, b_ih0 + (tn + 1) * 64, b_hh0 + (tn + 1) * 64,
                      nullptr, 0, Cb + (tn + 1) * 64, H, W4 + 4096, A4);
      }
    } else {
      int t = p - 4;
      if (t >= 0 && t < S) {
        const float* hp = h1 + (size_t)(t & 1) * GBH + (size_t)tb * 16 * H;
        float* C = out + ((size_t)(gb0 + tb * 16) * S + t) * V + tn * 64;
        tile_mm<H, 3>(tid, hp, nullptr, nullptr, b_out + tn * 64, nullptr,
                      nullptr, 0, C, (size_t)S * V, W4, A4);
      }
    }
    gbar(slots, r, bt++, tid);
  }

  // h_n = [h0[S-1], h1[S-1]]  (slot (S-1)&1 == 1)
  {
    float* hn = out + (size_t)B * S * V;
    const float* h0f = h0 + (size_t)GBH;
    const float* h1f = h1 + (size_t)GBH;
    for (size_t i = (size_t)r * 256 + tid; i < (size_t)GBH; i += (size_t)WPG * 256) {
      size_t bb = i >> 9, hh = i & 511;
      hn[(size_t)(gb0 + bb) * H + hh] = h0f[i];
      hn[(size_t)B * H + (size_t)(gb0 + bb) * H + hh] = h1f[i];
    }
  }
}

extern "C" void kernel_launch(void* const* d_in, const int* in_sizes, int n_in,
                              void* d_out, int out_size, void* d_ws, size_t ws_size,
                              hipStream_t stream) {
  const int*   x     = (const int*)d_in[0];
  const float* emb   = (const float*)d_in[1];
  const float* W_ih0 = (const float*)d_in[2];
  const float* b_ih0 = (const float*)d_in[3];
  const float* W_hh0 = (const float*)d_in[4];
  const float* b_hh0 = (const float*)d_in[5];
  const float* W_ih1 = (const float*)d_in[6];
  const float* b_ih1 = (const float*)d_in[7];
  const float* W_hh1 = (const float*)d_in[8];
  const float* b_hh1 = (const float*)d_in[9];
  const float* W_out = (const float*)d_in[10];
  const float* b_out = (const float*)d_in[11];
  float* out = (float*)d_out;
  float* ws  = (float*)d_ws;

  hipFuncSetAttribute((const void*)rnn_pers,
                      hipFuncAttributeMaxDynamicSharedMemorySize, (int)LDS_BYTES);
  // Zero barrier slots (4 groups x 64 u32).
  hipMemsetAsync(ws, 0, 256 * sizeof(unsigned), stream);

  void* args[] = { &x, &emb, &W_ih0, &b_ih0, &W_hh0, &b_hh0, &W_ih1, &b_ih1,
                   &W_hh1, &b_hh1, &W_out, &b_out, &out, &ws };
  hipLaunchCooperativeKernel((const void*)rnn_pers, dim3(NWG), dim3(256),
                             args, LDS_BYTES, stream);
}

// Round 4
// 18431.908 us; speedup vs baseline: 2.5672x; 1.4012x over previous
//
#include <hip/hip_runtime.h>

// Problem sizes (fixed by the reference)
constexpr int B = 128, S = 1024, E = 256, H = 512, V = 128;
constexpr int NGROUP = 8, WPG = 30, NWG = 256;  // 8 groups x 32 slots (30 live, 2 spare exit)
constexpr int GB = B / NGROUP;                  // 16 batch rows per group
constexpr int GBH = GB * H;                     // 8192 floats per (group, slot)
constexpr unsigned LDS_BYTES = 163840;          // 128KB weights + 32KB acts == 160KB

// ---- system-scope (cross-XCD coherent, no fences) memory helpers ------------
// sc0 sc1 loads/stores operate at the system coherence point (Infinity Cache):
// correct for cross-WG communication regardless of WG->XCD placement, with no
// L2 writeback/invalidate anywhere.

__device__ __forceinline__ void stg_sys(float* p, float v) {
  asm volatile("global_store_dword %0, %1, off sc0 sc1" :: "v"(p), "v"(v) : "memory");
}

__device__ __forceinline__ void load8_sys(
    const float* p0, const float* p1, const float* p2, const float* p3,
    const float* p4, const float* p5, const float* p6, const float* p7,
    float4& o0, float4& o1, float4& o2, float4& o3,
    float4& o4, float4& o5, float4& o6, float4& o7) {
  asm volatile(
      "global_load_dwordx4 %0, %8, off sc0 sc1\n\t"
      "global_load_dwordx4 %1, %9, off sc0 sc1\n\t"
      "global_load_dwordx4 %2, %10, off sc0 sc1\n\t"
      "global_load_dwordx4 %3, %11, off sc0 sc1\n\t"
      "global_load_dwordx4 %4, %12, off sc0 sc1\n\t"
      "global_load_dwordx4 %5, %13, off sc0 sc1\n\t"
      "global_load_dwordx4 %6, %14, off sc0 sc1\n\t"
      "global_load_dwordx4 %7, %15, off sc0 sc1\n\t"
      "s_waitcnt vmcnt(0)"
      : "=&v"(o0), "=&v"(o1), "=&v"(o2), "=&v"(o3),
        "=&v"(o4), "=&v"(o5), "=&v"(o6), "=&v"(o7)
      : "v"(p0), "v"(p1), "v"(p2), "v"(p3), "v"(p4), "v"(p5), "v"(p6), "v"(p7)
      : "memory");
}

// Group barrier: per-WG flag slot, no RMW, no fences. Writer: all-thread
// vmcnt(0) (drain own sc stores) -> tid0 stores phase counter sc0 sc1.
// Poll: wave0 lanes read the 30 slots sc0 sc1 until all >= target.
__device__ __forceinline__ void gbar(unsigned* slots, int r, unsigned target, int tid) {
  asm volatile("s_waitcnt vmcnt(0)" ::: "memory");
  __syncthreads();
  if (tid < 64) {
    if (tid == 0)
      asm volatile("global_store_dword %0, %1, off sc0 sc1"
                   :: "v"(slots + r), "v"(target) : "memory");
    for (;;) {
      unsigned v = target;
      if (tid < WPG)
        asm volatile("global_load_dword %0, %1, off sc0 sc1\n\ts_waitcnt vmcnt(0)"
                     : "=v"(v) : "v"(slots + tid) : "memory");
      if (__all((int)(v >= target))) break;
      __builtin_amdgcn_s_sleep(2);
    }
  }
  __syncthreads();
}

// Preload a 64-col x KK-k fp32 weight tile into LDS, XOR-swizzled per 16-float4
// window (bank-conflict-free for the per-lane b128 reads; measured 0 conflicts
// in rounds 2-3). Read-only -> normal cached loads.
template <int KK>
__device__ __forceinline__ void preload_W(int tid, const float* W, int n0, float4* dst) {
  constexpr int KC = KK / 4;
  for (int i = tid; i < 64 * KC; i += 256) {
    int c = i / KC, kc = i - c * KC;
    int swz = (kc & ~15) | ((kc ^ c) & 15);
    dst[(size_t)c * KC + swz] = *(const float4*)(W + (size_t)(n0 + c) * KK + 4 * kc);
  }
}

// One 16b x 64n output tile, K=KK, weights resident in LDS (W4).
// MODE 0: acts = emb rows gathered via xs[rr*S]; + bias1+bias2   (Ain)   KK=256
// MODE 1: acts from A (state); + initm (state); tanh             (h0/h1) KK=512
// MODE 2: acts from A (state); + bias1+bias2                     (G)     KK=512
// MODE 3: acts from A (state); + bias1                           (logits)KK=512
// CSTATE: C written with system-scope stores (cross-WG-visible state).
template <int KK, int MODE, bool CSTATE>
__device__ __forceinline__ void tile_mm(
    int tid,
    const float* A,                   // MODE!=0: act rows, stride H
    const int* xs, const float* emb_, // MODE==0
    const float* bias1, const float* bias2,
    const float* initm,               // MODE==1: pre-offset tile base, stride H
    float* C, size_t ldc,
    float* C2,                        // MODE==1 optional duplicate (h_n), stride H
    const float4* W4, float4* A4)
{
  constexpr int KC = KK / 4;
  float im0 = 0.f, im1 = 0.f, im2 = 0.f, im3 = 0.f;

  if (MODE == 0) {
#pragma unroll
    for (int j = 0; j < 4; ++j) {
      int e = tid + j * 256;
      int rr = e >> 6, kc = e & 63;
      A4[e] = *(const float4*)(emb_ + (size_t)xs[(size_t)rr * S] * E + 4 * kc);
    }
  } else {
    static_assert(MODE == 0 || KC == 128, "state tiles are K=512");
    if (MODE == 1) {
      // prefetch init values; the staging block's vmcnt(0) covers these too
      const float* q0 = initm + (size_t)((tid      ) >> 6) * H + ((tid      ) & 63);
      const float* q1 = initm + (size_t)((tid + 256) >> 6) * H + ((tid + 256) & 63);
      const float* q2 = initm + (size_t)((tid + 512) >> 6) * H + ((tid + 512) & 63);
      const float* q3 = initm + (size_t)((tid + 768) >> 6) * H + ((tid + 768) & 63);
      asm volatile(
          "global_load_dword %0, %4, off sc0 sc1\n\t"
          "global_load_dword %1, %5, off sc0 sc1\n\t"
          "global_load_dword %2, %6, off sc0 sc1\n\t"
          "global_load_dword %3, %7, off sc0 sc1"
          : "=&v"(im0), "=&v"(im1), "=&v"(im2), "=&v"(im3)
          : "v"(q0), "v"(q1), "v"(q2), "v"(q3)
          : "memory");
    }
    const float* p0 = A + (size_t)((tid       ) >> 7) * H + 4 * ((tid       ) & 127);
    const float* p1 = A + (size_t)((tid +  256) >> 7) * H + 4 * ((tid +  256) & 127);
    const float* p2 = A + (size_t)((tid +  512) >> 7) * H + 4 * ((tid +  512) & 127);
    const float* p3 = A + (size_t)((tid +  768) >> 7) * H + 4 * ((tid +  768) & 127);
    const float* p4 = A + (size_t)((tid + 1024) >> 7) * H + 4 * ((tid + 1024) & 127);
    const float* p5 = A + (size_t)((tid + 1280) >> 7) * H + 4 * ((tid + 1280) & 127);
    const float* p6 = A + (size_t)((tid + 1536) >> 7) * H + 4 * ((tid + 1536) & 127);
    const float* p7 = A + (size_t)((tid + 1792) >> 7) * H + 4 * ((tid + 1792) & 127);
    float4 o0, o1, o2, o3, o4, o5, o6, o7;
    load8_sys(p0, p1, p2, p3, p4, p5, p6, p7, o0, o1, o2, o3, o4, o5, o6, o7);
    A4[tid] = o0;         A4[tid +  256] = o1;  A4[tid +  512] = o2;
    A4[tid +  768] = o3;  A4[tid + 1024] = o4;  A4[tid + 1280] = o5;
    A4[tid + 1536] = o6;  A4[tid + 1792] = o7;
  }
  __syncthreads();

  const int c = tid & 63, q = tid >> 6;
  constexpr int SL = KC / 4;  // k-chunks per wave (k-split across 4 waves)
  float acc[16];
#pragma unroll
  for (int rr = 0; rr < 16; ++rr) acc[rr] = 0.f;
  const float4* Wrow = W4 + (size_t)c * KC;
  for (int kc = q * SL; kc < (q + 1) * SL; ++kc) {
    float4 w4 = Wrow[(kc & ~15) | ((kc ^ c) & 15)];
#pragma unroll
    for (int rr = 0; rr < 16; ++rr) {
      float4 a4 = A4[rr * KC + kc];  // wave-uniform -> broadcast
      acc[rr] += w4.x * a4.x + w4.y * a4.y + w4.z * a4.z + w4.w * a4.w;
    }
  }

  __syncthreads();                  // acts consumed; A4 becomes reduce buffer
  float* red = (float*)A4;
#pragma unroll
  for (int rr = 0; rr < 16; ++rr) red[(q * 16 + rr) * 64 + c] = acc[rr];
  __syncthreads();

#pragma unroll
  for (int j = 0; j < 4; ++j) {
    int o = tid + j * 256;
    int rr = o >> 6, cc = o & 63;
    float v = red[rr * 64 + cc] + red[(16 + rr) * 64 + cc] +
              red[(32 + rr) * 64 + cc] + red[(48 + rr) * 64 + cc];
    float im = (j == 0) ? im0 : (j == 1) ? im1 : (j == 2) ? im2 : im3;
    if (MODE == 1)      v = tanhf(v + im);
    else if (MODE == 3) v += bias1[cc];
    else                v += bias1[cc] + bias2[cc];
    if (CSTATE) stg_sys(C + (size_t)rr * ldc + cc, v);
    else        C[(size_t)rr * ldc + cc] = v;
    if (MODE == 1 && C2) C2[(size_t)rr * H + cc] = v;  // h_n duplicate
  }
  __syncthreads();  // protect A4 before a same-phase second tile restages
}

// Roles within a 30-WG group (B'=16, single b-tile):
//  r [0,8)   : h0-stage  t=p-1   h0[t]=tanh(Ain[t] + h0[t-1]@W_hh0^T)
//  r [8,16)  : G-stage   t=p-2   G[t]=b_ih1+b_hh1 + h0[t]@W_ih1^T
//  r [16,24) : h1-stage  t=p-3   h1[t]=tanh(G[t] + h1[t-1]@W_hh1^T)
//  r [24,28) : Ain-stage t=p     Ain[t]=b_ih0+b_hh0 + emb[x[:,t]]@W_ih0^T (2 tiles)
//  r [28,30) : logits    t=p-4   out[t]=b_out + h1[t]@W_out^T
__global__ void __launch_bounds__(256, 1) rnn_pers(
    const int* __restrict__ x, const float* __restrict__ emb,
    const float* __restrict__ W_ih0, const float* __restrict__ b_ih0,
    const float* __restrict__ W_hh0, const float* __restrict__ b_hh0,
    const float* __restrict__ W_ih1, const float* __restrict__ b_ih1,
    const float* __restrict__ W_hh1, const float* __restrict__ b_hh1,
    const float* __restrict__ W_out, const float* __restrict__ b_out,
    float* __restrict__ out, float* __restrict__ ws)
{
  extern __shared__ float4 dynlds[];
  float4* W4 = dynlds;          // 8192 float4 (128KB)
  float4* A4 = dynlds + 8192;   // 2048 float4 (32KB)

  const int tid = threadIdx.x;
  const int g = blockIdx.x >> 5;
  const int r = blockIdx.x & 31;
  if (r >= WPG) return;  // spares exit immediately

  unsigned* slots = (unsigned*)ws + (size_t)g * 64;
  float* st = ws + 1024 + (size_t)g * (8 * (size_t)GBH);
  float* Ain = st;                       // [2][16][512]
  float* h0  = st + 2 * (size_t)GBH;
  float* Gg  = st + 4 * (size_t)GBH;
  float* h1  = st + 6 * (size_t)GBH;
  const int gb0 = g * GB;

  int role, tn;
  if (r < 8)       { role = 1; tn = r;      preload_W<H>(tid, W_hh0, tn * 64, W4); }
  else if (r < 16) { role = 2; tn = r - 8;  preload_W<H>(tid, W_ih1, tn * 64, W4); }
  else if (r < 24) { role = 3; tn = r - 16; preload_W<H>(tid, W_hh1, tn * 64, W4); }
  else if (r < 28) { role = 0; tn = (r - 24) * 2;
                     preload_W<E>(tid, W_ih0, tn * 64, W4);
                     preload_W<E>(tid, W_ih0, (tn + 1) * 64, W4 + 4096); }
  else             { role = 4; tn = r - 28; preload_W<H>(tid, W_out, tn * 64, W4); }

  // Zero both slots of h0/h1 with system-scope stores (readers bypass caches).
  for (int i = r * 256 + tid; i < 2 * GBH; i += WPG * 256) {
    stg_sys(h0 + i, 0.f);
    stg_sys(h1 + i, 0.f);
  }
  unsigned bt = 1;
  gbar(slots, r, bt++, tid);

  float* hn = out + (size_t)B * S * V;

  for (int p = 0; p <= S + 3; ++p) {
    if (role == 1) {
      int t = p - 1;
      if (t >= 0 && t < S) {
        const float* hp = h0 + (size_t)((t - 1) & 1) * GBH;  // t=0 -> zeroed slot 1
        const float* im = Ain + (size_t)(t & 1) * GBH + tn * 64;
        float* C  = h0 + (size_t)(t & 1) * GBH + tn * 64;
        float* C2 = (t == S - 1) ? (hn + (size_t)gb0 * H + tn * 64) : nullptr;
        tile_mm<H, 1, true>(tid, hp, nullptr, nullptr, nullptr, nullptr, im,
                            C, H, C2, W4, A4);
      }
    } else if (role == 2) {
      int t = p - 2;
      if (t >= 0 && t < S) {
        const float* hp = h0 + (size_t)(t & 1) * GBH;
        float* C = Gg + (size_t)(t & 1) * GBH + tn * 64;
        tile_mm<H, 2, true>(tid, hp, nullptr, nullptr, b_ih1 + tn * 64, b_hh1 + tn * 64,
                            nullptr, C, H, nullptr, W4, A4);
      }
    } else if (role == 3) {
      int t = p - 3;
      if (t >= 0 && t < S) {
        const float* hp = h1 + (size_t)((t - 1) & 1) * GBH;
        const float* im = Gg + (size_t)(t & 1) * GBH + tn * 64;
        float* C  = h1 + (size_t)(t & 1) * GBH + tn * 64;
        float* C2 = (t == S - 1) ? (hn + (size_t)B * H + (size_t)gb0 * H + tn * 64) : nullptr;
        tile_mm<H, 1, true>(tid, hp, nullptr, nullptr, nullptr, nullptr, im,
                            C, H, C2, W4, A4);
      }
    } else if (role == 0) {
      int t = p;
      if (t < S) {
        const int* xs = x + (size_t)gb0 * S + t;
        float* Cb = Ain + (size_t)(t & 1) * GBH;
        tile_mm<E, 0, true>(tid, nullptr, xs, emb, b_ih0 + tn * 64, b_hh0 + tn * 64,
                            nullptr, Cb + tn * 64, H, nullptr, W4, A4);
        tile_mm<E, 0, true>(tid, nullptr, xs, emb, b_ih0 + (tn + 1) * 64, b_hh0 + (tn + 1) * 64,
                            nullptr, Cb + (tn + 1) * 64, H, nullptr, W4 + 4096, A4);
      }
    } else {
      int t = p - 4;
      if (t >= 0 && t < S) {
        const float* hp = h1 + (size_t)(t & 1) * GBH;
        float* C = out + ((size_t)gb0 * S + t) * V + tn * 64;
        tile_mm<H, 3, false>(tid, hp, nullptr, nullptr, b_out + tn * 64, nullptr,
                             nullptr, C, (size_t)S * V, nullptr, W4, A4);
      }
    }
    gbar(slots, r, bt++, tid);
  }
}

extern "C" void kernel_launch(void* const* d_in, const int* in_sizes, int n_in,
                              void* d_out, int out_size, void* d_ws, size_t ws_size,
                              hipStream_t stream) {
  const int*   x     = (const int*)d_in[0];
  const float* emb   = (const float*)d_in[1];
  const float* W_ih0 = (const float*)d_in[2];
  const float* b_ih0 = (const float*)d_in[3];
  const float* W_hh0 = (const float*)d_in[4];
  const float* b_hh0 = (const float*)d_in[5];
  const float* W_ih1 = (const float*)d_in[6];
  const float* b_ih1 = (const float*)d_in[7];
  const float* W_hh1 = (const float*)d_in[8];
  const float* b_hh1 = (const float*)d_in[9];
  const float* W_out = (const float*)d_in[10];
  const float* b_out = (const float*)d_in[11];
  float* out = (float*)d_out;
  float* ws  = (float*)d_ws;

  hipFuncSetAttribute((const void*)rnn_pers,
                      hipFuncAttributeMaxDynamicSharedMemorySize, (int)LDS_BYTES);
  // Zero the barrier flag region (ws is poisoned to 0xAA by the harness).
  hipMemsetAsync(ws, 0, 4096, stream);

  void* args[] = { &x, &emb, &W_ih0, &b_ih0, &W_hh0, &b_hh0, &W_ih1, &b_ih1,
                   &W_hh1, &b_hh1, &W_out, &b_out, &out, &ws };
  hipLaunchCooperativeKernel((const void*)rnn_pers, dim3(NWG), dim3(256),
                             args, LDS_BYTES, stream);
}

// Round 5
// 4874.878 us; speedup vs baseline: 9.7067x; 3.7810x over previous
//
#include <hip/hip_runtime.h>

// Problem sizes (fixed by the reference)
constexpr int B = 128, S = 1024, E = 256, H = 512, V = 128;
constexpr int NGROUP = 8, WPG = 30, NWG = 256;  // 8 groups x 32 slots (30 live)
constexpr int GB = B / NGROUP;                  // 16 batch rows per group
constexpr unsigned LDS_BYTES = 163840;          // 128KB weights + 32KB acts

using short8 = __attribute__((ext_vector_type(8))) short;   // 8 bf16 = 4 VGPRs
using f32x4  = __attribute__((ext_vector_type(4))) float;   // MFMA acc
using u16    = unsigned short;

#define MFMA_B16(a, b, c) __builtin_amdgcn_mfma_f32_16x16x32_bf16((a), (b), (c), 0, 0, 0)

// LDS layout (bytes): WH[64K] | WL[64K] | AH[16K] | AL[16K]
constexpr int LWH = 0, LWL = 65536, LAH = 131072, LAL = 147456;

// ---- bf16 hi/lo split helpers (truncation split: v = hi + lo, ~2^-16 rel) --
__device__ __forceinline__ unsigned pk(float a, float b) {
  return (__builtin_bit_cast(unsigned, b) & 0xFFFF0000u) |
         (__builtin_bit_cast(unsigned, a) >> 16);
}
__device__ __forceinline__ float hif(float a) {
  return __builtin_bit_cast(float, __builtin_bit_cast(unsigned, a) & 0xFFFF0000u);
}
__device__ __forceinline__ void cvt16(const float4& v0, const float4& v1,
                                      const float4& v2, const float4& v3,
                                      uint4& h0, uint4& h1, uint4& l0, uint4& l1) {
  h0 = make_uint4(pk(v0.x, v0.y), pk(v0.z, v0.w), pk(v1.x, v1.y), pk(v1.z, v1.w));
  h1 = make_uint4(pk(v2.x, v2.y), pk(v2.z, v2.w), pk(v3.x, v3.y), pk(v3.z, v3.w));
  l0 = make_uint4(pk(v0.x - hif(v0.x), v0.y - hif(v0.y)),
                  pk(v0.z - hif(v0.z), v0.w - hif(v0.w)),
                  pk(v1.x - hif(v1.x), v1.y - hif(v1.y)),
                  pk(v1.z - hif(v1.z), v1.w - hif(v1.w)));
  l1 = make_uint4(pk(v2.x - hif(v2.x), v2.y - hif(v2.y)),
                  pk(v2.z - hif(v2.z), v2.w - hif(v2.w)),
                  pk(v3.x - hif(v3.x), v3.y - hif(v3.y)),
                  pk(v3.z - hif(v3.z), v3.w - hif(v3.w)));
}

// ---- system-scope (cross-XCD, fence-free) memory helpers --------------------
__device__ __forceinline__ void stg_sys_f32(float* p, float v) {
  asm volatile("global_store_dword %0, %1, off sc0 sc1" :: "v"(p), "v"(v) : "memory");
}
__device__ __forceinline__ void stg_sys_u32(unsigned* p, unsigned v) {
  asm volatile("global_store_dword %0, %1, off sc0 sc1" :: "v"(p), "v"(v) : "memory");
}
__device__ __forceinline__ void stg_sys_u16(u16* p, unsigned v) {
  asm volatile("global_store_short %0, %1, off sc0 sc1" :: "v"(p), "v"(v) : "memory");
}

// Group barrier: per-WG flag slot, no RMW, no cache-maintenance fences.
__device__ __forceinline__ void gbar(unsigned* slots, int r, unsigned target, int tid) {
  asm volatile("s_waitcnt vmcnt(0)" ::: "memory");
  __syncthreads();
  if (tid < 64) {
    if (tid == 0)
      asm volatile("global_store_dword %0, %1, off sc0 sc1"
                   :: "v"(slots + r), "v"(target) : "memory");
    for (;;) {
      unsigned v = target;
      if (tid < WPG)
        asm volatile("global_load_dword %0, %1, off sc0 sc1\n\ts_waitcnt vmcnt(0)"
                     : "=v"(v) : "v"(slots + tid) : "memory");
      if (__all((int)(v >= target))) break;
      __builtin_amdgcn_s_sleep(2);
    }
  }
  __syncthreads();
}

// ---- weight preload: fp32 [NC][KK] -> LDS bf16 hi/lo planes, XOR-swizzled ---
template <int NC, int KK>
__device__ __forceinline__ void preload_Wb(int tid, const float* W, int n0,
                                           char* WH, char* WL) {
  constexpr int QPR = KK / 16;   // 16-float chunks per row
  constexpr int ROWB = KK * 2;   // bytes per bf16 row
  for (int cid = tid; cid < NC * QPR; cid += 256) {
    int rr = cid / QPR, q = cid % QPR;
    const float4* src = (const float4*)(W + (size_t)(n0 + rr) * KK + q * 16);
    float4 v0 = src[0], v1 = src[1], v2 = src[2], v3 = src[3];
    uint4 h0, h1, l0, l1;
    cvt16(v0, v1, v2, v3, h0, h1, l0, l1);
    int bb = rr * ROWB + q * 32, sw = (rr & 7) << 4;
    *(uint4*)(WH + ((bb) ^ sw)) = h0;
    *(uint4*)(WH + ((bb + 16) ^ sw)) = h1;
    *(uint4*)(WL + ((bb) ^ sw)) = l0;
    *(uint4*)(WL + ((bb + 16) ^ sw)) = l1;
  }
}

// ---- stage bf16 hi/lo state planes ([16][512] u16 each) into LDS ------------
__device__ __forceinline__ void compute_offs(int tid, int* off, int* lof) {
#pragma unroll
  for (int it = 0; it < 4; ++it) {
    int s = tid + it * 256, rr = s >> 6, ks = s & 63;
    off[it] = rr * 1024 + ks * 16;
    lof[it] = off[it] ^ ((rr & 7) << 4);
  }
}
__device__ __forceinline__ void stage8(int tid, const u16* Ph, const u16* Pl,
                                       char* AH, char* AL) {
  int off[4], lof[4];
  compute_offs(tid, off, lof);
  const char* gh = (const char*)Ph;
  const char* gl = (const char*)Pl;
  float4 o0, o1, o2, o3, o4, o5, o6, o7;
  asm volatile(
      "global_load_dwordx4 %0, %8, off sc0 sc1\n\t"
      "global_load_dwordx4 %1, %9, off sc0 sc1\n\t"
      "global_load_dwordx4 %2, %10, off sc0 sc1\n\t"
      "global_load_dwordx4 %3, %11, off sc0 sc1\n\t"
      "global_load_dwordx4 %4, %12, off sc0 sc1\n\t"
      "global_load_dwordx4 %5, %13, off sc0 sc1\n\t"
      "global_load_dwordx4 %6, %14, off sc0 sc1\n\t"
      "global_load_dwordx4 %7, %15, off sc0 sc1\n\t"
      "s_waitcnt vmcnt(0)"
      : "=&v"(o0), "=&v"(o1), "=&v"(o2), "=&v"(o3),
        "=&v"(o4), "=&v"(o5), "=&v"(o6), "=&v"(o7)
      : "v"(gh + off[0]), "v"(gh + off[1]), "v"(gh + off[2]), "v"(gh + off[3]),
        "v"(gl + off[0]), "v"(gl + off[1]), "v"(gl + off[2]), "v"(gl + off[3])
      : "memory");
  *(float4*)(AH + lof[0]) = o0; *(float4*)(AH + lof[1]) = o1;
  *(float4*)(AH + lof[2]) = o2; *(float4*)(AH + lof[3]) = o3;
  *(float4*)(AL + lof[0]) = o4; *(float4*)(AL + lof[1]) = o5;
  *(float4*)(AL + lof[2]) = o6; *(float4*)(AL + lof[3]) = o7;
}
// Same + 4 scalar fp32 init loads (one vmcnt for all 12).
__device__ __forceinline__ void stage12(int tid, const u16* Ph, const u16* Pl,
                                        char* AH, char* AL,
                                        const float* q0, const float* q1,
                                        const float* q2, const float* q3,
                                        float& i0, float& i1, float& i2, float& i3) {
  int off[4], lof[4];
  compute_offs(tid, off, lof);
  const char* gh = (const char*)Ph;
  const char* gl = (const char*)Pl;
  float4 o0, o1, o2, o3, o4, o5, o6, o7;
  asm volatile(
      "global_load_dword %8, %20, off sc0 sc1\n\t"
      "global_load_dword %9, %21, off sc0 sc1\n\t"
      "global_load_dword %10, %22, off sc0 sc1\n\t"
      "global_load_dword %11, %23, off sc0 sc1\n\t"
      "global_load_dwordx4 %0, %12, off sc0 sc1\n\t"
      "global_load_dwordx4 %1, %13, off sc0 sc1\n\t"
      "global_load_dwordx4 %2, %14, off sc0 sc1\n\t"
      "global_load_dwordx4 %3, %15, off sc0 sc1\n\t"
      "global_load_dwordx4 %4, %16, off sc0 sc1\n\t"
      "global_load_dwordx4 %5, %17, off sc0 sc1\n\t"
      "global_load_dwordx4 %6, %18, off sc0 sc1\n\t"
      "global_load_dwordx4 %7, %19, off sc0 sc1\n\t"
      "s_waitcnt vmcnt(0)"
      : "=&v"(o0), "=&v"(o1), "=&v"(o2), "=&v"(o3),
        "=&v"(o4), "=&v"(o5), "=&v"(o6), "=&v"(o7),
        "=&v"(i0), "=&v"(i1), "=&v"(i2), "=&v"(i3)
      : "v"(gh + off[0]), "v"(gh + off[1]), "v"(gh + off[2]), "v"(gh + off[3]),
        "v"(gl + off[0]), "v"(gl + off[1]), "v"(gl + off[2]), "v"(gl + off[3]),
        "v"(q0), "v"(q1), "v"(q2), "v"(q3)
      : "memory");
  *(float4*)(AH + lof[0]) = o0; *(float4*)(AH + lof[1]) = o1;
  *(float4*)(AH + lof[2]) = o2; *(float4*)(AH + lof[3]) = o3;
  *(float4*)(AL + lof[0]) = o4; *(float4*)(AL + lof[1]) = o5;
  *(float4*)(AL + lof[2]) = o6; *(float4*)(AL + lof[3]) = o7;
}

// ---- bf16x3 MFMA fragment loop: one 16x16 C tile, full K ---------------------
template <int KK>
__device__ __forceinline__ f32x4 mm_frag(const char* WH, const char* WL,
                                         const char* AH, const char* AL,
                                         int lane, int lcol0) {
  constexpr int ROWB = KK * 2;
  const int rr = lane & 15;
  const int lc = lcol0 + rr;          // weight row (output col), local
  const int kq = (lane >> 4) * 16;    // k-quarter byte offset within k-step
  const int swa = (rr & 7) << 4, sww = (lc & 7) << 4;
  f32x4 a0 = {0.f, 0.f, 0.f, 0.f}, a1 = {0.f, 0.f, 0.f, 0.f};
#pragma unroll
  for (int ks = 0; ks < KK / 32; ++ks) {
    int ka = rr * ROWB + ks * 64 + kq;
    int kw = lc * ROWB + ks * 64 + kq;
    short8 ah = *(const short8*)(AH + (ka ^ swa));
    short8 al = *(const short8*)(AL + (ka ^ swa));
    short8 wh = *(const short8*)(WH + (kw ^ sww));
    short8 wl = *(const short8*)(WL + (kw ^ sww));
    a0 = MFMA_B16(ah, wh, a0);
    a1 = MFMA_B16(ah, wl, a1);
    a1 = MFMA_B16(al, wh, a1);
  }
  return a0 + a1;
}

// Roles within a 30-WG group (16 batch rows):
//  r [0,8)   : h0-stage  t=p-1 ; r [8,16): G-stage t=p-2 ; r [16,24): h1-stage t=p-3
//  r [24,28) : Ain-stage t=p (128 cols each) ; r [28,30): logits t=p-4
__global__ void __launch_bounds__(256, 1) rnn_pers(
    const int* __restrict__ x, const float* __restrict__ emb,
    const float* __restrict__ W_ih0, const float* __restrict__ b_ih0,
    const float* __restrict__ W_hh0, const float* __restrict__ b_hh0,
    const float* __restrict__ W_ih1, const float* __restrict__ b_ih1,
    const float* __restrict__ W_hh1, const float* __restrict__ b_hh1,
    const float* __restrict__ W_out, const float* __restrict__ b_out,
    float* __restrict__ out, float* __restrict__ ws)
{
  extern __shared__ char lds[];
  char* WH = lds + LWH; char* WL = lds + LWL;
  char* AH = lds + LAH; char* AL = lds + LAL;

  const int tid = threadIdx.x;
  const int g = blockIdx.x >> 5;
  const int r = blockIdx.x & 31;
  if (r >= WPG) return;

  unsigned* slots = (unsigned*)ws + (size_t)g * 64;
  float* base = ws + 1024 + (size_t)g * 65536;
  float* Ain = base;                     // fp32 [2][16][512]
  float* Gg  = base + 16384;             // fp32 [2][16][512]
  u16* h0h = (u16*)(base + 32768);       // bf16-hi [2][16][512]
  u16* h0l = h0h + 16384;
  u16* h1h = h0h + 32768;
  u16* h1l = h0h + 49152;
  const int gb0 = g * GB;

  int role, tn;
  if (r < 8)       { role = 1; tn = r;          preload_Wb<64, 512>(tid, W_hh0, tn * 64, WH, WL); }
  else if (r < 16) { role = 2; tn = r - 8;      preload_Wb<64, 512>(tid, W_ih1, tn * 64, WH, WL); }
  else if (r < 24) { role = 3; tn = r - 16;     preload_Wb<64, 512>(tid, W_hh1, tn * 64, WH, WL); }
  else if (r < 28) { role = 0; tn = (r - 24)*2; preload_Wb<128, 256>(tid, W_ih0, tn * 64, WH, WL); }
  else             { role = 4; tn = r - 28;     preload_Wb<64, 512>(tid, W_out, tn * 64, WH, WL); }

  // Zero h-state planes (both slots, 4 planes = 32768 u32).
  {
    unsigned* zp = (unsigned*)h0h;
    for (int i = r * 256 + tid; i < 32768; i += WPG * 256) stg_sys_u32(zp + i, 0u);
  }
  unsigned bt = 1;
  gbar(slots, r, bt++, tid);

  const int lane = tid & 63, w = tid >> 6;
  const int lc15 = lane & 15, r0 = (lane >> 4) * 4;
  float* hn = out + (size_t)B * S * V;

  for (int p = 0; p <= S + 3; ++p) {
    if (role == 1 || role == 3) {
      int t = p - ((role == 1) ? 1 : 3);
      if (t >= 0 && t < S) {
        const u16* Ph = (role == 1 ? h0h : h1h) + ((t - 1) & 1) * 8192;
        const u16* Pl = (role == 1 ? h0l : h1l) + ((t - 1) & 1) * 8192;
        const float* im = (role == 1 ? Ain : Gg) + (t & 1) * 8192;
        const int gcol = tn * 64 + w * 16 + lc15;
        const float* iq = im + (size_t)r0 * H + gcol;
        float i0, i1, i2, i3;
        stage12(tid, Ph, Pl, AH, AL, iq, iq + H, iq + 2 * H, iq + 3 * H, i0, i1, i2, i3);
        __syncthreads();
        f32x4 s = mm_frag<512>(WH, WL, AH, AL, lane, w * 16);
        u16* Dh = (role == 1 ? h0h : h1h) + (t & 1) * 8192;
        u16* Dl = (role == 1 ? h0l : h1l) + (t & 1) * 8192;
        float* hn2 = nullptr;
        if (t == S - 1)
          hn2 = hn + ((role == 1) ? 0 : (size_t)B * H) + (size_t)gb0 * H;
        float iv[4] = {i0, i1, i2, i3};
#pragma unroll
        for (int j = 0; j < 4; ++j) {
          float v = tanhf(s[j] + iv[j]);
          unsigned ub = __builtin_bit_cast(unsigned, v);
          float lov = v - __builtin_bit_cast(float, ub & 0xFFFF0000u);
          stg_sys_u16(Dh + (size_t)(r0 + j) * H + gcol, ub >> 16);
          stg_sys_u16(Dl + (size_t)(r0 + j) * H + gcol,
                      __builtin_bit_cast(unsigned, lov) >> 16);
          if (hn2) hn2[(size_t)(r0 + j) * H + gcol] = v;
        }
      }
    } else if (role == 2) {
      int t = p - 2;
      if (t >= 0 && t < S) {
        const u16* Ph = h0h + (t & 1) * 8192;
        const u16* Pl = h0l + (t & 1) * 8192;
        stage8(tid, Ph, Pl, AH, AL);
        __syncthreads();
        f32x4 s = mm_frag<512>(WH, WL, AH, AL, lane, w * 16);
        const int gcol = tn * 64 + w * 16 + lc15;
        float bsum = b_ih1[gcol] + b_hh1[gcol];
        float* D = Gg + (t & 1) * 8192;
#pragma unroll
        for (int j = 0; j < 4; ++j)
          stg_sys_f32(D + (size_t)(r0 + j) * H + gcol, s[j] + bsum);
      }
    } else if (role == 0) {
      int t = p;
      if (t < S) {
        // stage emb rows (gathered) as hi/lo, K=256
        {
          int rr = tid >> 4, q = tid & 15;
          int idx = x[(size_t)(gb0 + rr) * S + t];
          const float4* src = (const float4*)(emb + (size_t)idx * E + q * 16);
          float4 v0 = src[0], v1 = src[1], v2 = src[2], v3 = src[3];
          uint4 h0v, h1v, l0v, l1v;
          cvt16(v0, v1, v2, v3, h0v, h1v, l0v, l1v);
          int bb = rr * 512 + q * 32, sw = (rr & 7) << 4;
          *(uint4*)(AH + ((bb) ^ sw)) = h0v;
          *(uint4*)(AH + ((bb + 16) ^ sw)) = h1v;
          *(uint4*)(AL + ((bb) ^ sw)) = l0v;
          *(uint4*)(AL + ((bb + 16) ^ sw)) = l1v;
        }
        __syncthreads();
        float* D = Ain + (t & 1) * 8192;
#pragma unroll
        for (int tt = 0; tt < 2; ++tt) {
          f32x4 s = mm_frag<256>(WH, WL, AH, AL, lane, w * 32 + tt * 16);
          const int gcol = tn * 64 + w * 32 + tt * 16 + lc15;
          float bsum = b_ih0[gcol] + b_hh0[gcol];
#pragma unroll
          for (int j = 0; j < 4; ++j)
            stg_sys_f32(D + (size_t)(r0 + j) * H + gcol, s[j] + bsum);
        }
      }
    } else {  // role 4: logits
      int t = p - 4;
      if (t >= 0 && t < S) {
        const u16* Ph = h1h + (t & 1) * 8192;
        const u16* Pl = h1l + (t & 1) * 8192;
        stage8(tid, Ph, Pl, AH, AL);
        __syncthreads();
        f32x4 s = mm_frag<512>(WH, WL, AH, AL, lane, w * 16);
        const int gcol = tn * 64 + w * 16 + lc15;
        float bv = b_out[gcol];
#pragma unroll
        for (int j = 0; j < 4; ++j)
          out[((size_t)(gb0 + r0 + j) * S + t) * V + gcol] = s[j] + bv;
      }
    }
    gbar(slots, r, bt++, tid);
  }
}

extern "C" void kernel_launch(void* const* d_in, const int* in_sizes, int n_in,
                              void* d_out, int out_size, void* d_ws, size_t ws_size,
                              hipStream_t stream) {
  const int*   x     = (const int*)d_in[0];
  const float* emb   = (const float*)d_in[1];
  const float* W_ih0 = (const float*)d_in[2];
  const float* b_ih0 = (const float*)d_in[3];
  const float* W_hh0 = (const float*)d_in[4];
  const float* b_hh0 = (const float*)d_in[5];
  const float* W_ih1 = (const float*)d_in[6];
  const float* b_ih1 = (const float*)d_in[7];
  const float* W_hh1 = (const float*)d_in[8];
  const float* b_hh1 = (const float*)d_in[9];
  const float* W_out = (const float*)d_in[10];
  const float* b_out = (const float*)d_in[11];
  float* out = (float*)d_out;
  float* ws  = (float*)d_ws;

  hipFuncSetAttribute((const void*)rnn_pers,
                      hipFuncAttributeMaxDynamicSharedMemorySize, (int)LDS_BYTES);
  hipMemsetAsync(ws, 0, 4096, stream);  // barrier flags

  void* args[] = { &x, &emb, &W_ih0, &b_ih0, &W_hh0, &b_hh0, &W_ih1, &b_ih1,
                   &W_hh1, &b_hh1, &W_out, &b_out, &out, &ws };
  hipLaunchCooperativeKernel((const void*)rnn_pers, dim3(NWG), dim3(256),
                             args, LDS_BYTES, stream);
}

// Round 7
// 4784.215 us; speedup vs baseline: 9.8906x; 1.0190x over previous
//
#include <hip/hip_runtime.h>

// Problem sizes (fixed by the reference)
constexpr int B = 128, S = 1024, E = 256, H = 512, V = 128;
constexpr int NGROUP = 8, WPG = 30, NWG = 256;  // 8 groups x 32 slots (30 live)
constexpr int GB = B / NGROUP;                  // 16 batch rows per group
constexpr unsigned LDS_BYTES = 32768;           // AH 16KB + AL 16KB

using short8 = __attribute__((ext_vector_type(8))) short;   // 8 bf16 = 4 VGPRs
using f32x4  = __attribute__((ext_vector_type(4))) float;   // MFMA acc
using u16    = unsigned short;

#define MFMA_B16(a, b, c) __builtin_amdgcn_mfma_f32_16x16x32_bf16((a), (b), (c), 0, 0, 0)

// ---- bf16 hi/lo split helpers (v = hi + lo, ~2^-16 rel error) ---------------
__device__ __forceinline__ unsigned pk(float a, float b) {
  return (__builtin_bit_cast(unsigned, b) & 0xFFFF0000u) |
         (__builtin_bit_cast(unsigned, a) >> 16);
}
__device__ __forceinline__ float hif(float a) {
  return __builtin_bit_cast(float, __builtin_bit_cast(unsigned, a) & 0xFFFF0000u);
}
__device__ __forceinline__ void cvt16(const float4& v0, const float4& v1,
                                      const float4& v2, const float4& v3,
                                      uint4& h0, uint4& h1, uint4& l0, uint4& l1) {
  h0 = make_uint4(pk(v0.x, v0.y), pk(v0.z, v0.w), pk(v1.x, v1.y), pk(v1.z, v1.w));
  h1 = make_uint4(pk(v2.x, v2.y), pk(v2.z, v2.w), pk(v3.x, v3.y), pk(v3.z, v3.w));
  l0 = make_uint4(pk(v0.x - hif(v0.x), v0.y - hif(v0.y)),
                  pk(v0.z - hif(v0.z), v0.w - hif(v0.w)),
                  pk(v1.x - hif(v1.x), v1.y - hif(v1.y)),
                  pk(v1.z - hif(v1.z), v1.w - hif(v1.w)));
  l1 = make_uint4(pk(v2.x - hif(v2.x), v2.y - hif(v2.y)),
                  pk(v2.z - hif(v2.z), v2.w - hif(v2.w)),
                  pk(v3.x - hif(v3.x), v3.y - hif(v3.y)),
                  pk(v3.z - hif(v3.z), v3.w - hif(v3.w)));
}

// ---- system-scope (cross-XCD, fence-free) memory helpers --------------------
__device__ __forceinline__ void stg_sys_f32(float* p, float v) {
  asm volatile("global_store_dword %0, %1, off sc0 sc1" :: "v"(p), "v"(v) : "memory");
}
__device__ __forceinline__ void stg_sys_u32(unsigned* p, unsigned v) {
  asm volatile("global_store_dword %0, %1, off sc0 sc1" :: "v"(p), "v"(v) : "memory");
}
__device__ __forceinline__ void stg_sys_u16(u16* p, unsigned v) {
  asm volatile("global_store_short %0, %1, off sc0 sc1" :: "v"(p), "v"(v) : "memory");
}

// Group barrier: per-WG flag slot, no RMW, no cache-maintenance fences.
// vmcnt(0) drains this thread's sc stores; tid0 publishes; wave0 polls all 30.
__device__ __forceinline__ void gbar(unsigned* slots, int r, unsigned target, int tid) {
  asm volatile("s_waitcnt vmcnt(0)" ::: "memory");
  __syncthreads();
  if (tid < 64) {
    if (tid == 0)
      asm volatile("global_store_dword %0, %1, off sc0 sc1"
                   :: "v"(slots + r), "v"(target) : "memory");
    for (;;) {
      unsigned v = target;
      if (tid < WPG)
        asm volatile("global_load_dword %0, %1, off sc0 sc1\n\ts_waitcnt vmcnt(0)"
                     : "=v"(v) : "v"(slots + tid) : "memory");
      if (__all((int)(v >= target))) break;
      __builtin_amdgcn_s_sleep(1);
    }
  }
  __syncthreads();
}

// ---- W fragment -> registers: lane (lc=col0+(lane&15), q=lane>>4) holds
// W[lc][ks*32 + q*8 .. +8] as bf16 hi/lo short8 per ks. Loaded once. ----------
template <int KK>
__device__ __forceinline__ void loadWfrag(const float* W, int col0, int lane,
                                          short8* wh, short8* wl) {
  const int lc = col0 + (lane & 15);
  const int q = lane >> 4;
#pragma unroll
  for (int ks = 0; ks < KK / 32; ++ks) {
    const float* src = W + (size_t)lc * KK + ks * 32 + q * 8;
    float4 a = *(const float4*)src;
    float4 b = *(const float4*)(src + 4);
    uint4 h = make_uint4(pk(a.x, a.y), pk(a.z, a.w), pk(b.x, b.y), pk(b.z, b.w));
    uint4 l = make_uint4(pk(a.x - hif(a.x), a.y - hif(a.y)),
                         pk(a.z - hif(a.z), a.w - hif(a.w)),
                         pk(b.x - hif(b.x), b.y - hif(b.y)),
                         pk(b.z - hif(b.z), b.w - hif(b.w)));
    wh[ks] = __builtin_bit_cast(short8, h);
    wl[ks] = __builtin_bit_cast(short8, l);
  }
}

// ---- A staging: bf16 hi/lo state planes ([16][512] u16) -> LDS --------------
__device__ __forceinline__ void compute_offs(int tid, int* off, int* lof) {
#pragma unroll
  for (int it = 0; it < 4; ++it) {
    int s = tid + it * 256, rr = s >> 6, ks = s & 63;
    off[it] = rr * 1024 + ks * 16;
    lof[it] = off[it] ^ ((rr & 7) << 4);
  }
}
__device__ __forceinline__ void stage8(int tid, const u16* Ph, const u16* Pl,
                                       char* AH, char* AL) {
  int off[4], lof[4];
  compute_offs(tid, off, lof);
  const char* gh = (const char*)Ph;
  const char* gl = (const char*)Pl;
  float4 o0, o1, o2, o3, o4, o5, o6, o7;
  asm volatile(
      "global_load_dwordx4 %0, %8, off sc0 sc1\n\t"
      "global_load_dwordx4 %1, %9, off sc0 sc1\n\t"
      "global_load_dwordx4 %2, %10, off sc0 sc1\n\t"
      "global_load_dwordx4 %3, %11, off sc0 sc1\n\t"
      "global_load_dwordx4 %4, %12, off sc0 sc1\n\t"
      "global_load_dwordx4 %5, %13, off sc0 sc1\n\t"
      "global_load_dwordx4 %6, %14, off sc0 sc1\n\t"
      "global_load_dwordx4 %7, %15, off sc0 sc1\n\t"
      "s_waitcnt vmcnt(0)"
      : "=&v"(o0), "=&v"(o1), "=&v"(o2), "=&v"(o3),
        "=&v"(o4), "=&v"(o5), "=&v"(o6), "=&v"(o7)
      : "v"(gh + off[0]), "v"(gh + off[1]), "v"(gh + off[2]), "v"(gh + off[3]),
        "v"(gl + off[0]), "v"(gl + off[1]), "v"(gl + off[2]), "v"(gl + off[3])
      : "memory");
  *(float4*)(AH + lof[0]) = o0; *(float4*)(AH + lof[1]) = o1;
  *(float4*)(AH + lof[2]) = o2; *(float4*)(AH + lof[3]) = o3;
  *(float4*)(AL + lof[0]) = o4; *(float4*)(AL + lof[1]) = o5;
  *(float4*)(AL + lof[2]) = o6; *(float4*)(AL + lof[3]) = o7;
}
__device__ __forceinline__ void stage12(int tid, const u16* Ph, const u16* Pl,
                                        char* AH, char* AL,
                                        const float* q0, const float* q1,
                                        const float* q2, const float* q3,
                                        float& i0, float& i1, float& i2, float& i3) {
  int off[4], lof[4];
  compute_offs(tid, off, lof);
  const char* gh = (const char*)Ph;
  const char* gl = (const char*)Pl;
  float4 o0, o1, o2, o3, o4, o5, o6, o7;
  asm volatile(
      "global_load_dword %8, %20, off sc0 sc1\n\t"
      "global_load_dword %9, %21, off sc0 sc1\n\t"
      "global_load_dword %10, %22, off sc0 sc1\n\t"
      "global_load_dword %11, %23, off sc0 sc1\n\t"
      "global_load_dwordx4 %0, %12, off sc0 sc1\n\t"
      "global_load_dwordx4 %1, %13, off sc0 sc1\n\t"
      "global_load_dwordx4 %2, %14, off sc0 sc1\n\t"
      "global_load_dwordx4 %3, %15, off sc0 sc1\n\t"
      "global_load_dwordx4 %4, %16, off sc0 sc1\n\t"
      "global_load_dwordx4 %5, %17, off sc0 sc1\n\t"
      "global_load_dwordx4 %6, %18, off sc0 sc1\n\t"
      "global_load_dwordx4 %7, %19, off sc0 sc1\n\t"
      "s_waitcnt vmcnt(0)"
      : "=&v"(o0), "=&v"(o1), "=&v"(o2), "=&v"(o3),
        "=&v"(o4), "=&v"(o5), "=&v"(o6), "=&v"(o7),
        "=&v"(i0), "=&v"(i1), "=&v"(i2), "=&v"(i3)
      : "v"(gh + off[0]), "v"(gh + off[1]), "v"(gh + off[2]), "v"(gh + off[3]),
        "v"(gl + off[0]), "v"(gl + off[1]), "v"(gl + off[2]), "v"(gl + off[3]),
        "v"(q0), "v"(q1), "v"(q2), "v"(q3)
      : "memory");
  *(float4*)(AH + lof[0]) = o0; *(float4*)(AH + lof[1]) = o1;
  *(float4*)(AH + lof[2]) = o2; *(float4*)(AH + lof[3]) = o3;
  *(float4*)(AL + lof[0]) = o4; *(float4*)(AL + lof[1]) = o5;
  *(float4*)(AL + lof[2]) = o6; *(float4*)(AL + lof[3]) = o7;
}

// ---- bf16x3 MFMA loop: A from LDS, W from registers -------------------------
template <int KK>
__device__ __forceinline__ f32x4 mm_frag_reg(const char* AH, const char* AL,
                                             const short8* wh, const short8* wl,
                                             int lane) {
  constexpr int ROWB = KK * 2;
  const int rr = lane & 15;
  const int kq = (lane >> 4) * 16;
  const int swa = (rr & 7) << 4;
  f32x4 a0 = {0.f, 0.f, 0.f, 0.f}, a1 = {0.f, 0.f, 0.f, 0.f};
#pragma unroll
  for (int ks = 0; ks < KK / 32; ++ks) {
    int ka = rr * ROWB + ks * 64 + kq;
    short8 ah = *(const short8*)(AH + (ka ^ swa));
    short8 al = *(const short8*)(AL + (ka ^ swa));
    a0 = MFMA_B16(ah, wh[ks], a0);
    a1 = MFMA_B16(ah, wl[ks], a1);
    a1 = MFMA_B16(al, wh[ks], a1);
  }
  return a0 + a1;
}

// ---- per-role phase loops ---------------------------------------------------
// role h (h0: dt=1, h1: dt=3): h[t] = tanh(im[t] + h[t-1] @ W^T)
__device__ __forceinline__ void run_h(
    int tid, int lane, int w, unsigned* slots, int r, int dt,
    u16* hh, u16* hl, const float* imb, float* hn2base,
    const float* Wsrc, int tn, char* AH, char* AL) {
  short8 wh[16], wl[16];
  loadWfrag<512>(Wsrc, tn * 64 + w * 16, lane, wh, wl);
  gbar(slots, r, 1, tid);
  const int lc15 = lane & 15, r0 = (lane >> 4) * 4;
  const int gcol = tn * 64 + w * 16 + lc15;
  for (int p = 0; p <= S + 3; ++p) {
    int t = p - dt;
    if (t >= 0 && t < S) {
      const u16* Ph = hh + ((t - 1) & 1) * 8192;
      const u16* Pl = hl + ((t - 1) & 1) * 8192;
      const float* iq = imb + (t & 1) * 8192 + (size_t)r0 * H + gcol;
      float i0, i1, i2, i3;
      stage12(tid, Ph, Pl, AH, AL, iq, iq + H, iq + 2 * H, iq + 3 * H, i0, i1, i2, i3);
      __syncthreads();
      f32x4 s = mm_frag_reg<512>(AH, AL, wh, wl, lane);
      u16* Dh = hh + (t & 1) * 8192;
      u16* Dl = hl + (t & 1) * 8192;
      float iv[4] = {i0, i1, i2, i3};
      bool last = (t == S - 1);
#pragma unroll
      for (int j = 0; j < 4; ++j) {
        float v = tanhf(s[j] + iv[j]);
        unsigned ub = __builtin_bit_cast(unsigned, v);
        float lov = v - __builtin_bit_cast(float, ub & 0xFFFF0000u);
        stg_sys_u16(Dh + (size_t)(r0 + j) * H + gcol, ub >> 16);
        stg_sys_u16(Dl + (size_t)(r0 + j) * H + gcol,
                    __builtin_bit_cast(unsigned, lov) >> 16);
        if (last) hn2base[(size_t)(r0 + j) * H + gcol] = v;
      }
    }
    gbar(slots, r, 2 + p, tid);
  }
}

// role G: G[t] = b_ih1 + b_hh1 + h0[t] @ W_ih1^T  (fp32 out)
__device__ __forceinline__ void run_g(
    int tid, int lane, int w, unsigned* slots, int r,
    const u16* h0h, const u16* h0l, float* Gg,
    const float* b1, const float* b2,
    const float* Wsrc, int tn, char* AH, char* AL) {
  short8 wh[16], wl[16];
  loadWfrag<512>(Wsrc, tn * 64 + w * 16, lane, wh, wl);
  gbar(slots, r, 1, tid);
  const int lc15 = lane & 15, r0 = (lane >> 4) * 4;
  const int gcol = tn * 64 + w * 16 + lc15;
  const float bsum = b1[gcol] + b2[gcol];
  for (int p = 0; p <= S + 3; ++p) {
    int t = p - 2;
    if (t >= 0 && t < S) {
      stage8(tid, h0h + (t & 1) * 8192, h0l + (t & 1) * 8192, AH, AL);
      __syncthreads();
      f32x4 s = mm_frag_reg<512>(AH, AL, wh, wl, lane);
      float* D = Gg + (t & 1) * 8192;
#pragma unroll
      for (int j = 0; j < 4; ++j)
        stg_sys_f32(D + (size_t)(r0 + j) * H + gcol, s[j] + bsum);
    }
    gbar(slots, r, 2 + p, tid);
  }
}

// role Ain: Ain[t] = b_ih0 + b_hh0 + emb[x[:,t]] @ W_ih0^T  (128 cols per WG)
__device__ __forceinline__ void run_ain(
    int tid, int lane, int w, unsigned* slots, int r,
    const int* x, const float* emb, float* Ain,
    const float* b1, const float* b2,
    const float* Wsrc, int tn, int gb0, char* AH, char* AL) {
  short8 whA[8], wlA[8], whB[8], wlB[8];
  loadWfrag<256>(Wsrc, tn * 64 + w * 32, lane, whA, wlA);
  loadWfrag<256>(Wsrc, tn * 64 + w * 32 + 16, lane, whB, wlB);
  gbar(slots, r, 1, tid);
  const int lc15 = lane & 15, r0 = (lane >> 4) * 4;
  const int gcolA = tn * 64 + w * 32 + lc15, gcolB = gcolA + 16;
  const float bsA = b1[gcolA] + b2[gcolA], bsB = b1[gcolB] + b2[gcolB];
  const int rr = tid >> 4, q = tid & 15;
  for (int p = 0; p <= S + 3; ++p) {
    int t = p;
    if (t < S) {
      int idx = x[(size_t)(gb0 + rr) * S + t];
      const float4* src = (const float4*)(emb + (size_t)idx * E + q * 16);
      float4 v0 = src[0], v1 = src[1], v2 = src[2], v3 = src[3];
      uint4 h0v, h1v, l0v, l1v;
      cvt16(v0, v1, v2, v3, h0v, h1v, l0v, l1v);
      int bb = rr * 512 + q * 32, sw = (rr & 7) << 4;
      *(uint4*)(AH + ((bb) ^ sw)) = h0v;
      *(uint4*)(AH + ((bb + 16) ^ sw)) = h1v;
      *(uint4*)(AL + ((bb) ^ sw)) = l0v;
      *(uint4*)(AL + ((bb + 16) ^ sw)) = l1v;
      __syncthreads();
      f32x4 sA = mm_frag_reg<256>(AH, AL, whA, wlA, lane);
      f32x4 sB = mm_frag_reg<256>(AH, AL, whB, wlB, lane);
      float* D = Ain + (t & 1) * 8192;
#pragma unroll
      for (int j = 0; j < 4; ++j) {
        stg_sys_f32(D + (size_t)(r0 + j) * H + gcolA, sA[j] + bsA);
        stg_sys_f32(D + (size_t)(r0 + j) * H + gcolB, sB[j] + bsB);
      }
    }
    gbar(slots, r, 2 + p, tid);
  }
}

// role logits: out[t] = b_out + h1[t] @ W_out^T
__device__ __forceinline__ void run_out(
    int tid, int lane, int w, unsigned* slots, int r,
    const u16* h1h, const u16* h1l, float* out, const float* b_out,
    const float* Wsrc, int tn, int gb0, char* AH, char* AL) {
  short8 wh[16], wl[16];
  loadWfrag<512>(Wsrc, tn * 64 + w * 16, lane, wh, wl);
  gbar(slots, r, 1, tid);
  const int lc15 = lane & 15, r0 = (lane >> 4) * 4;
  const int gcol = tn * 64 + w * 16 + lc15;
  const float bv = b_out[gcol];
  for (int p = 0; p <= S + 3; ++p) {
    int t = p - 4;
    if (t >= 0 && t < S) {
      stage8(tid, h1h + (t & 1) * 8192, h1l + (t & 1) * 8192, AH, AL);
      __syncthreads();
      f32x4 s = mm_frag_reg<512>(AH, AL, wh, wl, lane);
#pragma unroll
      for (int j = 0; j < 4; ++j)
        out[((size_t)(gb0 + r0 + j) * S + t) * V + gcol] = s[j] + bv;
    }
    gbar(slots, r, 2 + p, tid);
  }
}

// Grouping by blockIdx (placement-independent correctness, G16).
// Roles within a 30-WG group (16 batch rows):
//  r [0,8): h0 t=p-1 | r [8,16): G t=p-2 | r [16,24): h1 t=p-3
//  r [24,28): Ain t=p (128 cols) | r [28,30): logits t=p-4
__global__ void __launch_bounds__(256, 1) rnn_pers(
    const int* __restrict__ x, const float* __restrict__ emb,
    const float* __restrict__ W_ih0, const float* __restrict__ b_ih0,
    const float* __restrict__ W_hh0, const float* __restrict__ b_hh0,
    const float* __restrict__ W_ih1, const float* __restrict__ b_ih1,
    const float* __restrict__ W_hh1, const float* __restrict__ b_hh1,
    const float* __restrict__ W_out, const float* __restrict__ b_out,
    float* __restrict__ out, float* __restrict__ ws)
{
  extern __shared__ char lds[];
  char* AH = lds;
  char* AL = lds + 16384;

  const int tid = threadIdx.x;
  const int g = blockIdx.x >> 5;
  const int r = blockIdx.x & 31;
  if (r >= WPG) return;

  unsigned* slots = (unsigned*)ws + (size_t)g * 64;
  float* base = ws + 1024 + (size_t)g * 65536;
  float* Ain = base;                 // fp32 [2][16][512]
  float* Gg  = base + 16384;         // fp32 [2][16][512]
  u16* h0h = (u16*)(base + 32768);   // bf16-hi/lo [2][16][512] x4 planes
  u16* h0l = h0h + 16384;
  u16* h1h = h0h + 32768;
  u16* h1l = h0h + 49152;
  const int gb0 = g * GB;

  // Zero h-state planes (both slots, 4 planes = 32768 u32), system scope.
  {
    unsigned* zp = (unsigned*)h0h;
    for (int i = r * 256 + tid; i < 32768; i += WPG * 256) stg_sys_u32(zp + i, 0u);
  }

  const int lane = tid & 63, w = tid >> 6;
  float* hn = out + (size_t)B * S * V;

  if (r < 8)
    run_h(tid, lane, w, slots, r, 1, h0h, h0l, Ain,
          hn + (size_t)gb0 * H, W_hh0, r, AH, AL);
  else if (r < 16)
    run_g(tid, lane, w, slots, r, h0h, h0l, Gg, b_ih1, b_hh1,
          W_ih1, r - 8, AH, AL);
  else if (r < 24)
    run_h(tid, lane, w, slots, r, 3, h1h, h1l, Gg,
          hn + (size_t)B * H + (size_t)gb0 * H, W_hh1, r - 16, AH, AL);
  else if (r < 28)
    run_ain(tid, lane, w, slots, r, x, emb, Ain, b_ih0, b_hh0,
            W_ih0, (r - 24) * 2, gb0, AH, AL);
  else
    run_out(tid, lane, w, slots, r, h1h, h1l, out, b_out,
            W_out, r - 28, gb0, AH, AL);
}

extern "C" void kernel_launch(void* const* d_in, const int* in_sizes, int n_in,
                              void* d_out, int out_size, void* d_ws, size_t ws_size,
                              hipStream_t stream) {
  const int*   x     = (const int*)d_in[0];
  const float* emb   = (const float*)d_in[1];
  const float* W_ih0 = (const float*)d_in[2];
  const float* b_ih0 = (const float*)d_in[3];
  const float* W_hh0 = (const float*)d_in[4];
  const float* b_hh0 = (const float*)d_in[5];
  const float* W_ih1 = (const float*)d_in[6];
  const float* b_ih1 = (const float*)d_in[7];
  const float* W_hh1 = (const float*)d_in[8];
  const float* b_hh1 = (const float*)d_in[9];
  const float* W_out = (const float*)d_in[10];
  const float* b_out = (const float*)d_in[11];
  float* out = (float*)d_out;
  float* ws  = (float*)d_ws;

  hipFuncSetAttribute((const void*)rnn_pers,
                      hipFuncAttributeMaxDynamicSharedMemorySize, (int)LDS_BYTES);
  hipMemsetAsync(ws, 0, 4096, stream);  // barrier flags

  void* args[] = { &x, &emb, &W_ih0, &b_ih0, &W_hh0, &b_hh0, &W_ih1, &b_ih1,
                   &W_hh1, &b_hh1, &W_out, &b_out, &out, &ws };
  hipLaunchCooperativeKernel((const void*)rnn_pers, dim3(NWG), dim3(256),
                             args, LDS_BYTES, stream);
}